// Round 4
// baseline (52.430 us; speedup 1.0000x reference)
//
#include <hip/hip_runtime.h>
#include <math.h>

// Two-phase fused GCN-attention, keys via wave-uniform (scalar) loads.
// K1: wave = 64 queries (1/lane) x node n x 128-key slice. Key rows are read with a
//     WAVE-UNIFORM pointer -> s_load into SGPRs (or 1 coalesced broadcast per wave);
//     inner loop is pure VALU: v_fmac(v_s, s_k, v_q). No LDS key traffic at all.
//     Block = 8 waves reduce partials (l, acc[10]) via small LDS rbuf -> ws.
// K2: combine 4 key-quarters + BN(eval) + adj-combine + GC weight + avgpool -> out.

constexpr int BTOT = 4096;
constexpr int NN = 3;
constexpr int DIM = 10;
constexpr int ROW = 30;          // floats per batch row (3 nodes x 10)
constexpr int QG = 64;           // queries per wave (one per lane)
constexpr int NQG = BTOT / QG;   // 64 query groups
constexpr int NGC = 4;           // key quarters (cross-block split)
constexpr int WAVES = 8;         // waves per block (within-block key split)
constexpr int T1 = WAVES * 64;   // 512 threads
constexpr int KPW = BTOT / NGC / WAVES;   // 128 keys per wave
constexpr float LOG2E = 1.4426950408889634f;
constexpr float SHIFT2 = 20.0f * LOG2E;   // fixed softmax shift, log2 domain
constexpr float EPS = 1e-5f;

__global__ __launch_bounds__(T1) void attn_partial(
    const float* __restrict__ x, float* __restrict__ ws)
{
    __shared__ float rbuf[WAVES][QG][13];   // 26.6 KB; 13-pad -> 2-way (free)

    const int bx = blockIdx.x;
    const int qg = bx / (NN * NGC);
    const int r  = bx % (NN * NGC);
    const int n  = r / NGC;
    const int gc = r % NGC;
    const int w  = __builtin_amdgcn_readfirstlane(threadIdx.x >> 6);  // force wave-uniform
    const int j  = threadIdx.x & 63;
    const int q  = qg * QG + j;

    // per-lane query row, pre-scaled to log2 domain
    float q2[DIM];
    {
        const float* qp = x + q * ROW + n * DIM;
        #pragma unroll
        for (int d = 0; d < DIM; d += 2) {
            float2 t = *(const float2*)(qp + d);
            q2[d]     = t.x * LOG2E;
            q2[d + 1] = t.y * LOG2E;
        }
    }

    float l = 0.f;
    float acc[DIM];
    #pragma unroll
    for (int d = 0; d < DIM; ++d) acc[d] = 0.f;

    // this wave's key slice: UNIFORM address stream -> scalar loads
    const int kbase = gc * (BTOT / NGC) + w * KPW;
    const float* kp = x + (size_t)kbase * ROW + n * DIM;
    #pragma unroll 4
    for (int kk = 0; kk < KPW; ++kk, kp += ROW) {
        float k[DIM];
        #pragma unroll
        for (int d = 0; d < DIM; ++d) k[d] = kp[d];   // uniform -> SGPRs
        float s = -SHIFT2;
        #pragma unroll
        for (int d = 0; d < DIM; ++d) s += q2[d] * k[d];
        float e = exp2f(s);
        l += e;
        #pragma unroll
        for (int d = 0; d < DIM; ++d) acc[d] += e * k[d];
    }

    // cross-wave reduction within block
    #pragma unroll
    for (int d = 0; d < DIM; ++d) rbuf[w][j][d] = acc[d];
    rbuf[w][j][DIM] = l;
    __syncthreads();

    // (DIM+1)*QG = 704 items, 512 threads: strided
    for (int t = threadIdx.x; t < (DIM + 1) * QG; t += T1) {
        int d  = t >> 6;
        int jj = t & 63;
        float s = 0.f;
        #pragma unroll
        for (int w2 = 0; w2 < WAVES; ++w2) s += rbuf[w2][jj][d];
        // ws layout: [(n*NGC+gc)*11 + d][4096 queries]  (coalesced both sides)
        ws[((size_t)((n * NGC + gc) * (DIM + 1) + d)) * BTOT + qg * QG + jj] = s;
    }
}

__global__ __launch_bounds__(256) void finalize(
    const float* __restrict__ ws, const float* __restrict__ A,
    const float* __restrict__ W, const float* __restrict__ bn_g,
    const float* __restrict__ bn_b, const float* __restrict__ bn_m,
    const float* __restrict__ bn_v, float* __restrict__ out)
{
    const int q = blockIdx.x * 256 + threadIdx.x;   // 4096 threads

    // wk[k] = 0.125*((1-d0k+A[0,k]) + (1-d1k+A[1,k]))
    float wk[NN];
    #pragma unroll
    for (int k = 0; k < NN; ++k) {
        float a0k = (k == 0 ? 0.f : 1.f) + A[0 * NN + k];
        float a1k = (k == 1 ? 0.f : 1.f) + A[1 * NN + k];
        wk[k] = 0.125f * (a0k + a1k);
    }

    float u[DIM];
    #pragma unroll
    for (int d = 0; d < DIM; ++d) u[d] = 0.f;

    #pragma unroll
    for (int n = 0; n < NN; ++n) {
        float l = 0.f;
        float a[DIM];
        #pragma unroll
        for (int d = 0; d < DIM; ++d) a[d] = 0.f;
        #pragma unroll
        for (int gc = 0; gc < NGC; ++gc) {
            const float* p = ws + ((size_t)((n * NGC + gc) * (DIM + 1))) * BTOT + q;
            #pragma unroll
            for (int d = 0; d < DIM; ++d) a[d] += p[(size_t)d * BTOT];
            l += p[(size_t)DIM * BTOT];
        }
        float inv = 1.0f / l;
        float sc = bn_g[n] * rsqrtf(bn_v[n] + EPS);
        float sh = bn_b[n] - bn_m[n] * sc;
        float cw = wk[n];
        #pragma unroll
        for (int d = 0; d < DIM; ++d) u[d] += cw * (a[d] * inv * sc + sh);
    }

    // out[q][dout] = sum_e u[e] * W[e][dout]
    #pragma unroll
    for (int dout = 0; dout < DIM; ++dout) {
        float o = 0.f;
        #pragma unroll
        for (int e = 0; e < DIM; ++e) o += u[e] * W[e * DIM + dout];
        out[q * DIM + dout] = o;
    }
}

extern "C" void kernel_launch(void* const* d_in, const int* in_sizes, int n_in,
                              void* d_out, int out_size, void* d_ws, size_t ws_size,
                              hipStream_t stream) {
    const float* x  = (const float*)d_in[0];
    const float* A  = (const float*)d_in[1];
    const float* W  = (const float*)d_in[2];
    const float* g  = (const float*)d_in[3];
    const float* be = (const float*)d_in[4];
    const float* mu = (const float*)d_in[5];
    const float* va = (const float*)d_in[6];
    float* out = (float*)d_out;
    float* ws  = (float*)d_ws;   // needs 12*11*4096*4 B = 2.07 MB

    hipLaunchKernelGGL(attn_partial, dim3(NQG * NN * NGC), dim3(T1), 0, stream, x, ws);
    hipLaunchKernelGGL(finalize, dim3(BTOT / 256), dim3(256), 0, stream,
                       ws, A, W, g, be, mu, va, out);
}

// Round 5
// 42.219 us; speedup vs baseline: 1.2419x; 1.2419x over previous
//
#include <hip/hip_runtime.h>
#include <math.h>

// Two-phase fused GCN-attention, ILP-restructured.
// K1: wave = 64 lanes x 2 queries/lane (rows q, q+64) x 128-key slice.
//     Keys staged in LDS once per chunk; compute reads are wave-uniform broadcasts.
//     Inner loop: explicit 4-key batches in named registers -> 8 independent
//     dot chains in flight (issue-bound, not latency-bound).
// K2: combine NGC key-slices + BN(eval) + adj + GC weight + avgpool -> out.

constexpr int BTOT = 4096;
constexpr int NN = 3;
constexpr int DIM = 10;
constexpr int ROW = 30;           // floats per batch row (3 nodes x 10)
constexpr int QPB = 128;          // queries per block (2 per lane)
constexpr int NQSB = BTOT / QPB;  // 32 query superblocks
constexpr int WAVES = 4;
constexpr int T1 = WAVES * 64;    // 256 threads
constexpr int CHUNK = 512;        // keys staged per LDS stage
constexpr int KSTR = 12;          // padded words per key (16B-aligned)
constexpr float LOG2E = 1.4426950408889634f;
constexpr float SHIFT2 = 20.0f * LOG2E;   // fixed softmax shift, log2 domain
constexpr float EPS = 1e-5f;

#if __has_builtin(__builtin_amdgcn_exp2f)
#define EXP2(x) __builtin_amdgcn_exp2f(x)
#else
#define EXP2(x) exp2f(x)
#endif

struct KeyRegs { float4 a; float4 b; float2 c; };

__device__ __forceinline__ void loadKey(const float* p, KeyRegs& k) {
    k.a = *(const float4*)p;
    k.b = *(const float4*)(p + 4);
    k.c = *(const float2*)(p + 8);
}
__device__ __forceinline__ float dot10(const float q[DIM], const KeyRegs& k) {
    float s = -SHIFT2;
    s = fmaf(q[0], k.a.x, s); s = fmaf(q[1], k.a.y, s);
    s = fmaf(q[2], k.a.z, s); s = fmaf(q[3], k.a.w, s);
    s = fmaf(q[4], k.b.x, s); s = fmaf(q[5], k.b.y, s);
    s = fmaf(q[6], k.b.z, s); s = fmaf(q[7], k.b.w, s);
    s = fmaf(q[8], k.c.x, s); s = fmaf(q[9], k.c.y, s);
    return s;
}
__device__ __forceinline__ void acc10(float a[DIM], const KeyRegs& k, float e) {
    a[0] = fmaf(e, k.a.x, a[0]); a[1] = fmaf(e, k.a.y, a[1]);
    a[2] = fmaf(e, k.a.z, a[2]); a[3] = fmaf(e, k.a.w, a[3]);
    a[4] = fmaf(e, k.b.x, a[4]); a[5] = fmaf(e, k.b.y, a[5]);
    a[6] = fmaf(e, k.b.z, a[6]); a[7] = fmaf(e, k.b.w, a[7]);
    a[8] = fmaf(e, k.c.x, a[8]); a[9] = fmaf(e, k.c.y, a[9]);
}

// NCHUNK=1 -> NGC=8 (512 keys/block); NCHUNK=2 -> NGC=4 (1024 keys/block)
template <int NCHUNK>
__global__ __launch_bounds__(T1, 3) void attn_partial(
    const float* __restrict__ x, float* __restrict__ ws)
{
    constexpr int NGC = 8 / NCHUNK;
    // union: kbuf (512*12 = 6144 floats) reused as rbuf (4*128*11 = 5632 floats)
    __shared__ __align__(16) float smem[CHUNK * KSTR];

    const int bx  = blockIdx.x;
    const int qsb = bx / (NN * NGC);
    const int r   = bx % (NN * NGC);
    const int n   = r / NGC;
    const int gc  = r % NGC;
    const int w   = threadIdx.x >> 6;
    const int j   = threadIdx.x & 63;

    // two query rows per lane, pre-scaled to log2 domain
    float qa[DIM], qb[DIM];
    {
        const float* pa = x + (qsb * QPB + j) * ROW + n * DIM;
        const float* pb = pa + 64 * ROW;
        #pragma unroll
        for (int d = 0; d < DIM; d += 2) {
            float2 ta = *(const float2*)(pa + d);
            float2 tb = *(const float2*)(pb + d);
            qa[d] = ta.x * LOG2E; qa[d + 1] = ta.y * LOG2E;
            qb[d] = tb.x * LOG2E; qb[d + 1] = tb.y * LOG2E;
        }
    }

    float la = 0.f, lb = 0.f;
    float acca[DIM], accb[DIM];
    #pragma unroll
    for (int d = 0; d < DIM; ++d) { acca[d] = 0.f; accb[d] = 0.f; }

    #pragma unroll
    for (int ch = 0; ch < NCHUNK; ++ch) {
        __syncthreads();
        // stage CHUNK keys (node n only) -> smem[key][12]
        {
            const int c0 = gc * (BTOT / NGC) + ch * CHUNK;
            const float* src = x + (size_t)c0 * ROW + n * DIM;
            #pragma unroll
            for (int i = 0; i < (CHUNK * 5) / T1; ++i) {   // 2560/256 = 10
                int idx = threadIdx.x + i * T1;
                int c = idx / 5, p = idx - c * 5;
                float2 t = *(const float2*)(src + c * ROW + 2 * p);
                *(float2*)&smem[c * KSTR + 2 * p] = t;
            }
        }
        __syncthreads();

        // this wave's 128-key slice, 4-key batches (broadcast reads)
        const float* kp0 = &smem[(w * 128) * KSTR];
        for (int kk = 0; kk < 128; kk += 4) {
            const float* kp = kp0 + kk * KSTR;
            KeyRegs k0, k1, k2, k3;
            loadKey(kp,             k0);
            loadKey(kp + KSTR,      k1);
            loadKey(kp + 2 * KSTR,  k2);
            loadKey(kp + 3 * KSTR,  k3);
            float sa0 = dot10(qa, k0), sb0 = dot10(qb, k0);
            float sa1 = dot10(qa, k1), sb1 = dot10(qb, k1);
            float sa2 = dot10(qa, k2), sb2 = dot10(qb, k2);
            float sa3 = dot10(qa, k3), sb3 = dot10(qb, k3);
            float ea0 = EXP2(sa0), eb0 = EXP2(sb0);
            float ea1 = EXP2(sa1), eb1 = EXP2(sb1);
            float ea2 = EXP2(sa2), eb2 = EXP2(sb2);
            float ea3 = EXP2(sa3), eb3 = EXP2(sb3);
            la += (ea0 + ea1) + (ea2 + ea3);
            lb += (eb0 + eb1) + (eb2 + eb3);
            acc10(acca, k0, ea0); acc10(accb, k0, eb0);
            acc10(acca, k1, ea1); acc10(accb, k1, eb1);
            acc10(acca, k2, ea2); acc10(accb, k2, eb2);
            acc10(acca, k3, ea3); acc10(accb, k3, eb3);
        }
    }

    // cross-wave reduce: overlay rbuf[4][128][11] on smem
    __syncthreads();   // all waves done reading kbuf
    float (*rbuf)[QPB][11] = (float (*)[QPB][11])smem;
    #pragma unroll
    for (int d = 0; d < DIM; ++d) {
        rbuf[w][j][d]      = acca[d];
        rbuf[w][j + 64][d] = accb[d];
    }
    rbuf[w][j][DIM]      = la;
    rbuf[w][j + 64][DIM] = lb;
    __syncthreads();

    // (DIM+1)*QPB = 1408 items, 256 threads: strided
    for (int t = threadIdx.x; t < (DIM + 1) * QPB; t += T1) {
        int d  = t >> 7;
        int jj = t & 127;
        float s = 0.f;
        #pragma unroll
        for (int w2 = 0; w2 < WAVES; ++w2) s += rbuf[w2][jj][d];
        ws[((size_t)((n * NGC + gc) * (DIM + 1) + d)) * BTOT + qsb * QPB + jj] = s;
    }
}

template <int NGC>
__global__ __launch_bounds__(256) void finalize(
    const float* __restrict__ ws, const float* __restrict__ A,
    const float* __restrict__ W, const float* __restrict__ bn_g,
    const float* __restrict__ bn_b, const float* __restrict__ bn_m,
    const float* __restrict__ bn_v, float* __restrict__ out)
{
    const int q = blockIdx.x * 256 + threadIdx.x;

    float wk[NN];
    #pragma unroll
    for (int k = 0; k < NN; ++k) {
        float a0k = (k == 0 ? 0.f : 1.f) + A[0 * NN + k];
        float a1k = (k == 1 ? 0.f : 1.f) + A[1 * NN + k];
        wk[k] = 0.125f * (a0k + a1k);
    }

    float u[DIM];
    #pragma unroll
    for (int d = 0; d < DIM; ++d) u[d] = 0.f;

    #pragma unroll
    for (int n = 0; n < NN; ++n) {
        float l = 0.f;
        float a[DIM];
        #pragma unroll
        for (int d = 0; d < DIM; ++d) a[d] = 0.f;
        #pragma unroll
        for (int gc = 0; gc < NGC; ++gc) {
            const float* p = ws + ((size_t)((n * NGC + gc) * (DIM + 1))) * BTOT + q;
            #pragma unroll
            for (int d = 0; d < DIM; ++d) a[d] += p[(size_t)d * BTOT];
            l += p[(size_t)DIM * BTOT];
        }
        float inv = 1.0f / l;
        float sc = bn_g[n] * rsqrtf(bn_v[n] + EPS);
        float sh = bn_b[n] - bn_m[n] * sc;
        float cw = wk[n];
        #pragma unroll
        for (int d = 0; d < DIM; ++d) u[d] += cw * (a[d] * inv * sc + sh);
    }

    #pragma unroll
    for (int dout = 0; dout < DIM; ++dout) {
        float o = 0.f;
        #pragma unroll
        for (int e = 0; e < DIM; ++e) o += u[e] * W[e * DIM + dout];
        out[q * DIM + dout] = o;
    }
}

extern "C" void kernel_launch(void* const* d_in, const int* in_sizes, int n_in,
                              void* d_out, int out_size, void* d_ws, size_t ws_size,
                              hipStream_t stream) {
    const float* x  = (const float*)d_in[0];
    const float* A  = (const float*)d_in[1];
    const float* W  = (const float*)d_in[2];
    const float* g  = (const float*)d_in[3];
    const float* be = (const float*)d_in[4];
    const float* mu = (const float*)d_in[5];
    const float* va = (const float*)d_in[6];
    float* out = (float*)d_out;
    float* ws  = (float*)d_ws;

    const size_t need8 = (size_t)NN * 8 * (DIM + 1) * BTOT * sizeof(float); // 4.33 MB
    if (ws_size >= need8) {
        hipLaunchKernelGGL((attn_partial<1>), dim3(NQSB * NN * 8), dim3(T1), 0, stream, x, ws);
        hipLaunchKernelGGL((finalize<8>), dim3(BTOT / 256), dim3(256), 0, stream,
                           ws, A, W, g, be, mu, va, out);
    } else {
        hipLaunchKernelGGL((attn_partial<2>), dim3(NQSB * NN * 4), dim3(T1), 0, stream, x, ws);
        hipLaunchKernelGGL((finalize<4>), dim3(BTOT / 256), dim3(256), 0, stream,
                           ws, A, W, g, be, mu, va, out);
    }
}

// Round 6
// 41.291 us; speedup vs baseline: 1.2698x; 1.0225x over previous
//
#include <hip/hip_runtime.h>
#include <math.h>

// Two-phase fused GCN-attention, wave-independent K1.
// K1: wave = 64 lanes x 2 queries/lane (rows q, q+64) x 64-key slice.
//     Each wave stages ITS OWN keys into a private LDS region -> no barriers in
//     the main loop (wave-local lgkmcnt ordering only). 2-key x 2-query batches
//     give 4 independent fma chains (issue-bound). One barrier before the
//     cross-wave reduce. 6144 waves -> 4 waves/SIMD resident.
// K2: combine SL key-slices + BN(eval) + adj + GC weight + avgpool -> out.
//     ws laid out [slice][q][12] so K2 reads are float4.

constexpr int BTOT = 4096;
constexpr int NN = 3;
constexpr int DIM = 10;
constexpr int ROW = 30;           // floats per batch row (3 nodes x 10)
constexpr int QPB = 128;          // queries per block (2 per lane)
constexpr int NQG = BTOT / QPB;   // 32 query groups
constexpr int WAVES = 4;
constexpr int T1 = WAVES * 64;    // 256 threads
constexpr int KW = 64;            // keys per wave-chunk
constexpr float LOG2E = 1.4426950408889634f;
constexpr float SHIFT2 = 20.0f * LOG2E;   // fixed softmax shift, log2 domain
constexpr float EPS = 1e-5f;

#if __has_builtin(__builtin_amdgcn_exp2f)
#define EXP2(x) __builtin_amdgcn_exp2f(x)
#else
#define EXP2(x) exp2f(x)
#endif

struct KeyRegs { float4 a; float4 b; float2 c; };

__device__ __forceinline__ void loadKey(const float* p, KeyRegs& k) {
    k.a = *(const float4*)p;
    k.b = *(const float4*)(p + 4);
    k.c = *(const float2*)(p + 8);
}
__device__ __forceinline__ float dot10(const float q[DIM], const KeyRegs& k) {
    float s = -SHIFT2;
    s = fmaf(q[0], k.a.x, s); s = fmaf(q[1], k.a.y, s);
    s = fmaf(q[2], k.a.z, s); s = fmaf(q[3], k.a.w, s);
    s = fmaf(q[4], k.b.x, s); s = fmaf(q[5], k.b.y, s);
    s = fmaf(q[6], k.b.z, s); s = fmaf(q[7], k.b.w, s);
    s = fmaf(q[8], k.c.x, s); s = fmaf(q[9], k.c.y, s);
    return s;
}
__device__ __forceinline__ void acc10(float a[DIM], const KeyRegs& k, float e) {
    a[0] = fmaf(e, k.a.x, a[0]); a[1] = fmaf(e, k.a.y, a[1]);
    a[2] = fmaf(e, k.a.z, a[2]); a[3] = fmaf(e, k.a.w, a[3]);
    a[4] = fmaf(e, k.b.x, a[4]); a[5] = fmaf(e, k.b.y, a[5]);
    a[6] = fmaf(e, k.b.z, a[6]); a[7] = fmaf(e, k.b.w, a[7]);
    a[8] = fmaf(e, k.c.x, a[8]); a[9] = fmaf(e, k.c.y, a[9]);
}

// CH = key-chunks per wave; slices per node SL = 16/CH. Wave handles CH*64 keys.
template <int CH>
__global__ __launch_bounds__(T1, 4) void attn_partial(
    const float* __restrict__ x, float* __restrict__ ws)
{
    constexpr int SL = 16 / CH;
    __shared__ __align__(16) float kbuf[WAVES][KW][12];   // 12 KB, per-wave private
    __shared__ float rbuf[WAVES][QPB][13];                // 26 KB, 13-pad (free)

    const int bx = blockIdx.x;
    const int qg = bx / (NN * SL);
    const int r  = bx % (NN * SL);
    const int n  = r / SL;
    const int gc = r % SL;
    const int w  = threadIdx.x >> 6;
    const int j  = threadIdx.x & 63;

    // two query rows per lane, pre-scaled to log2 domain (8B-aligned)
    float qa[DIM], qb[DIM];
    {
        const float* pa = x + (qg * QPB + j) * ROW + n * DIM;
        const float* pb = pa + 64 * ROW;
        #pragma unroll
        for (int d = 0; d < DIM; d += 2) {
            float2 ta = *(const float2*)(pa + d);
            float2 tb = *(const float2*)(pb + d);
            qa[d] = ta.x * LOG2E; qa[d + 1] = ta.y * LOG2E;
            qb[d] = tb.x * LOG2E; qb[d + 1] = tb.y * LOG2E;
        }
    }

    float la = 0.f, lb = 0.f;
    float acca[DIM], accb[DIM];
    #pragma unroll
    for (int d = 0; d < DIM; ++d) { acca[d] = 0.f; accb[d] = 0.f; }

    for (int ci = 0; ci < CH; ++ci) {
        // wave-private staging: lane j loads key kb+j (no barriers; lgkmcnt orders)
        const int kb = (gc * CH + ci) * (WAVES * KW) + w * KW;
        {
            const float* sp = x + (size_t)(kb + j) * ROW + n * DIM;  // 8B-aligned
            float2 r0 = *(const float2*)sp;
            float2 r1 = *(const float2*)(sp + 2);
            float2 r2 = *(const float2*)(sp + 4);
            float2 r3 = *(const float2*)(sp + 6);
            float2 r4 = *(const float2*)(sp + 8);
            float* kd = &kbuf[w][j][0];
            *(float4*)kd       = make_float4(r0.x, r0.y, r1.x, r1.y);
            *(float4*)(kd + 4) = make_float4(r2.x, r2.y, r3.x, r3.y);
            *(float2*)(kd + 8) = r4;
        }
        // 64 keys, 2-key x 2-query batches (broadcast LDS reads, conflict-free)
        const float* kp0 = &kbuf[w][0][0];
        #pragma unroll 2
        for (int kk = 0; kk < KW; kk += 2) {
            KeyRegs k0, k1;
            loadKey(kp0 + kk * 12,      k0);
            loadKey(kp0 + kk * 12 + 12, k1);
            float sa0 = dot10(qa, k0), sb0 = dot10(qb, k0);
            float sa1 = dot10(qa, k1), sb1 = dot10(qb, k1);
            float ea0 = EXP2(sa0), eb0 = EXP2(sb0);
            float ea1 = EXP2(sa1), eb1 = EXP2(sb1);
            la += ea0 + ea1;
            lb += eb0 + eb1;
            acc10(acca, k0, ea0); acc10(accb, k0, eb0);
            acc10(acca, k1, ea1); acc10(accb, k1, eb1);
        }
    }

    // cross-wave reduce (single barrier in the kernel)
    #pragma unroll
    for (int d = 0; d < DIM; ++d) {
        rbuf[w][j][d]      = acca[d];
        rbuf[w][j + 64][d] = accb[d];
    }
    rbuf[w][j][DIM]      = la;
    rbuf[w][j + 64][DIM] = lb;
    __syncthreads();

    // 11*128 = 1408 items over 256 threads; ws layout [slice][q][12] (float4-able)
    for (int t = threadIdx.x; t < (DIM + 1) * QPB; t += T1) {
        int d  = t >> 7;
        int jj = t & 127;
        float s = rbuf[0][jj][d] + rbuf[1][jj][d] + rbuf[2][jj][d] + rbuf[3][jj][d];
        ws[((size_t)(n * SL + gc) * BTOT + qg * QPB + jj) * 12 + d] = s;
    }
}

template <int SL>
__global__ __launch_bounds__(192) void finalize(
    const float* __restrict__ ws, const float* __restrict__ A,
    const float* __restrict__ W, const float* __restrict__ bn_g,
    const float* __restrict__ bn_b, const float* __restrict__ bn_m,
    const float* __restrict__ bn_v, float* __restrict__ out)
{
    __shared__ float ubuf[64][NN][13];
    const int tl = threadIdx.x;       // 192 = 64 queries x 3 nodes
    const int ql = tl & 63;
    const int n  = tl >> 6;
    const int q  = blockIdx.x * 64 + ql;

    float a[12];
    #pragma unroll
    for (int d = 0; d < 12; ++d) a[d] = 0.f;
    #pragma unroll
    for (int sl = 0; sl < SL; ++sl) {
        const float* p = ws + ((size_t)(n * SL + sl) * BTOT + q) * 12;
        float4 v0 = *(const float4*)p;
        float4 v1 = *(const float4*)(p + 4);
        float4 v2 = *(const float4*)(p + 8);
        a[0] += v0.x; a[1] += v0.y; a[2]  += v0.z; a[3]  += v0.w;
        a[4] += v1.x; a[5] += v1.y; a[6]  += v1.z; a[7]  += v1.w;
        a[8] += v2.x; a[9] += v2.y; a[10] += v2.z;
    }
    // BN + adj row-weight for this node
    float inv = 1.0f / a[10];
    float sc = bn_g[n] * rsqrtf(bn_v[n] + EPS);
    float sh = bn_b[n] - bn_m[n] * sc;
    float cw = 0.125f * (((n == 0) ? 0.f : 1.f) + A[n] +
                         ((n == 1) ? 0.f : 1.f) + A[NN + n]);
    #pragma unroll
    for (int d = 0; d < DIM; ++d)
        ubuf[ql][n][d] = cw * (a[d] * inv * sc + sh);
    __syncthreads();

    if (tl < 64) {
        float u[DIM];
        #pragma unroll
        for (int d = 0; d < DIM; ++d)
            u[d] = ubuf[ql][0][d] + ubuf[ql][1][d] + ubuf[ql][2][d];
        #pragma unroll
        for (int dout = 0; dout < DIM; ++dout) {
            float o = 0.f;
            #pragma unroll
            for (int e = 0; e < DIM; ++e) o = fmaf(u[e], W[e * DIM + dout], o);
            out[q * DIM + dout] = o;
        }
    }
}

extern "C" void kernel_launch(void* const* d_in, const int* in_sizes, int n_in,
                              void* d_out, int out_size, void* d_ws, size_t ws_size,
                              hipStream_t stream) {
    const float* x  = (const float*)d_in[0];
    const float* A  = (const float*)d_in[1];
    const float* W  = (const float*)d_in[2];
    const float* g  = (const float*)d_in[3];
    const float* be = (const float*)d_in[4];
    const float* mu = (const float*)d_in[5];
    const float* va = (const float*)d_in[6];
    float* out = (float*)d_out;
    float* ws  = (float*)d_ws;

    auto need = [](int SL) { return (size_t)NN * SL * BTOT * 12 * sizeof(float); };
    if (ws_size >= need(16)) {          // 9.44 MB
        hipLaunchKernelGGL((attn_partial<1>),  dim3(NQG * NN * 16), dim3(T1), 0, stream, x, ws);
        hipLaunchKernelGGL((finalize<16>), dim3(BTOT / 64), dim3(192), 0, stream,
                           ws, A, W, g, be, mu, va, out);
    } else if (ws_size >= need(4)) {    // 2.36 MB
        hipLaunchKernelGGL((attn_partial<4>),  dim3(NQG * NN * 4),  dim3(T1), 0, stream, x, ws);
        hipLaunchKernelGGL((finalize<4>),  dim3(BTOT / 64), dim3(192), 0, stream,
                           ws, A, W, g, be, mu, va, out);
    } else {                            // 0.59 MB
        hipLaunchKernelGGL((attn_partial<16>), dim3(NQG * NN * 1),  dim3(T1), 0, stream, x, ws);
        hipLaunchKernelGGL((finalize<1>),  dim3(BTOT / 64), dim3(192), 0, stream,
                           ws, A, W, g, be, mu, va, out);
    }
}